// Round 6
// baseline (961.533 us; speedup 1.0000x reference)
//
#include <hip/hip_runtime.h>
#include <cstdint>
#include <cstddef>

#define NPOINT 512
#define NSAMPLE 32
#define NPB 8192  // points per batch

// Inputs: float32. Outputs: float32 flat concat (new_xyz, new_idx,
// new_features, sample_ids). Selection math (FPS argmax, ball d2<r2) must be
// bit-exact vs numpy f32: __f*_rn ops, no FMA contraction, exact tie-breaks.
__device__ __forceinline__ unsigned short f2bf(float f) {
  unsigned int u = __float_as_uint(f);
  unsigned int r = u + 0x7FFFu + ((u >> 16) & 1u);  // RNE
  return (unsigned short)(r >> 16);
}

// ---------------------------------------------------------------- FPS
// One block (512 thr) per batch; thread t owns points [t*16, t*16+16) in
// registers. __launch_bounds__(512,2): 256-VGPR budget so px/py/pz/dist
// stay in registers (VGPR=60 in r5 => spilled to scratch, ~1300 cyc/iter).
// Per iter: exact dist update + fmax tree; wave shuffle-max; winning lane
// (lowest tied lane = smallest index) recovers its local index by scanning
// dist[] for == wmax, publishes {d,idx,xyz} to parity-buffered LDS; ONE
// barrier; all threads scan the 8 wave slots (strict > => smallest wid).
__global__ __launch_bounds__(512, 2) void k_fps(const float* __restrict__ xyz,
                                                float* __restrict__ out_xyz,
                                                float* __restrict__ out_idx) {
  const int b = blockIdx.x;
  const int t = threadIdx.x;
  const float* xb = xyz + (size_t)b * NPB * 3;

  float px[16], py[16], pz[16], dist[16];
  {
    const float4* gp = reinterpret_cast<const float4*>(xb + (size_t)t * 48);
    float comp[48];
#pragma unroll
    for (int v = 0; v < 12; ++v) {
      float4 r = gp[v];
      comp[v * 4 + 0] = r.x;
      comp[v * 4 + 1] = r.y;
      comp[v * 4 + 2] = r.z;
      comp[v * 4 + 3] = r.w;
    }
#pragma unroll
    for (int j = 0; j < 16; ++j) {
      px[j] = comp[3 * j + 0];
      py[j] = comp[3 * j + 1];
      pz[j] = comp[3 * j + 2];
      dist[j] = 1e10f;
    }
  }

  __shared__ __align__(16) float sD[2][8];
  __shared__ int sI[2][8];
  __shared__ float sX[2][8], sY[2][8], sZ[2][8];

  const int wid = t >> 6;
  const int lane = t & 63;

  float qx = xb[0], qy = xb[1], qz = xb[2];  // selection 0 = index 0
  if (t == 0) {
    out_idx[b * NPOINT + 0] = 0.0f;
    size_t o = (size_t)(b * NPOINT) * 3;
    out_xyz[o + 0] = qx; out_xyz[o + 1] = qy; out_xyz[o + 2] = qz;
  }

  for (int it = 1; it < NPOINT; ++it) {
    // exact numpy-f32 distance update (no fma, no reassoc)
#pragma unroll
    for (int j = 0; j < 16; ++j) {
      float dx = __fsub_rn(px[j], qx);
      float dy = __fsub_rn(py[j], qy);
      float dz = __fsub_rn(pz[j], qz);
      float d2 = __fadd_rn(__fadd_rn(__fmul_rn(dx, dx), __fmul_rn(dy, dy)), __fmul_rn(dz, dz));
      dist[j] = fminf(dist[j], d2);
    }
    // per-thread max via fmax tree (compiler forms v_max3)
    float m01 = fmaxf(dist[0], dist[1]),   m23 = fmaxf(dist[2], dist[3]);
    float m45 = fmaxf(dist[4], dist[5]),   m67 = fmaxf(dist[6], dist[7]);
    float m89 = fmaxf(dist[8], dist[9]),   mab = fmaxf(dist[10], dist[11]);
    float mcd = fmaxf(dist[12], dist[13]), mef = fmaxf(dist[14], dist[15]);
    float q0 = fmaxf(fmaxf(m01, m23), fmaxf(m45, m67));
    float q1 = fmaxf(fmaxf(m89, mab), fmaxf(mcd, mef));
    float best = fmaxf(q0, q1);
    // wave-level max
    float wmax = best;
#pragma unroll
    for (int off = 32; off >= 1; off >>= 1) wmax = fmaxf(wmax, __shfl_xor(wmax, off));
    const unsigned long long m = __ballot(best == wmax);
    const int p = it & 1;
    if (lane == (int)(__ffsll((unsigned long long)m) - 1)) {  // lowest tied lane
      int bi = 15;
#pragma unroll
      for (int j = 15; j >= 0; --j)
        if (dist[j] == wmax) bi = j;  // first (smallest) matching j
      sD[p][wid] = wmax;
      sI[p][wid] = t * 16 + bi;
      float sx_, sy_, sz_;
      switch (bi) {
        case 0:  sx_ = px[0];  sy_ = py[0];  sz_ = pz[0];  break;
        case 1:  sx_ = px[1];  sy_ = py[1];  sz_ = pz[1];  break;
        case 2:  sx_ = px[2];  sy_ = py[2];  sz_ = pz[2];  break;
        case 3:  sx_ = px[3];  sy_ = py[3];  sz_ = pz[3];  break;
        case 4:  sx_ = px[4];  sy_ = py[4];  sz_ = pz[4];  break;
        case 5:  sx_ = px[5];  sy_ = py[5];  sz_ = pz[5];  break;
        case 6:  sx_ = px[6];  sy_ = py[6];  sz_ = pz[6];  break;
        case 7:  sx_ = px[7];  sy_ = py[7];  sz_ = pz[7];  break;
        case 8:  sx_ = px[8];  sy_ = py[8];  sz_ = pz[8];  break;
        case 9:  sx_ = px[9];  sy_ = py[9];  sz_ = pz[9];  break;
        case 10: sx_ = px[10]; sy_ = py[10]; sz_ = pz[10]; break;
        case 11: sx_ = px[11]; sy_ = py[11]; sz_ = pz[11]; break;
        case 12: sx_ = px[12]; sy_ = py[12]; sz_ = pz[12]; break;
        case 13: sx_ = px[13]; sy_ = py[13]; sz_ = pz[13]; break;
        case 14: sx_ = px[14]; sy_ = py[14]; sz_ = pz[14]; break;
        default: sx_ = px[15]; sy_ = py[15]; sz_ = pz[15]; break;
      }
      sX[p][wid] = sx_; sY[p][wid] = sy_; sZ[p][wid] = sz_;
    }
    __syncthreads();  // the only barrier per iteration
    float bd = sD[p][0];
    int bw = 0;
#pragma unroll
    for (int w = 1; w < 8; ++w) {
      float d = sD[p][w];
      if (d > bd) { bd = d; bw = w; }
    }
    const int gbi = sI[p][bw];
    qx = sX[p][bw]; qy = sY[p][bw]; qz = sZ[p][bw];
    if (t == 0) {
      out_idx[b * NPOINT + it] = (float)gbi;
      size_t o = (size_t)(b * NPOINT + it) * 3;
      out_xyz[o + 0] = qx; out_xyz[o + 1] = qy; out_xyz[o + 2] = qz;
    }
  }
}

// ---------------------------------------------------------- feature transpose
// features f32 [64][Ntot] -> feat_t bf16 [Ntot][64]
__global__ __launch_bounds__(256) void k_transpose(const float* __restrict__ in,
                                                   unsigned short* __restrict__ out,
                                                   int Ntot) {
  __shared__ __align__(16) unsigned short tile[64][65];
  const int t = threadIdx.x;
  const int n0 = blockIdx.x * 64;
#pragma unroll
  for (int i = 0; i < 16; ++i) {
    int c = i * 4 + (t >> 6);
    int n = t & 63;
    tile[c][n] = f2bf(in[(size_t)c * Ntot + n0 + n]);
  }
  __syncthreads();
#pragma unroll
  for (int i = 0; i < 16; ++i) {
    int n = i * 4 + (t >> 6);
    int c = t & 63;
    out[(size_t)(n0 + n) * 64 + c] = tile[c][n];
  }
}

// ---------------------------------------------------------------- ball query
// One wave per center (8 waves/block). Fixed 64 rounds x 2 points/lane so
// loads pipeline across rounds. Ordered compaction via ballot+popcount.
__global__ __launch_bounds__(512) void k_ball(const float* __restrict__ xyz,
                                              const float* __restrict__ fps_idx_f,
                                              float* __restrict__ sids_f) {
  __shared__ int slots[8 * NSAMPLE];
  const int b = blockIdx.x >> 6;
  const int cbase = (blockIdx.x & 63) * 8;
  const int t = threadIdx.x;
  const float* xb = xyz + (size_t)b * NPB * 3;

  const int w = t >> 6, lane = t & 63;
  const int c_local = cbase + w;
  const int ci = (int)fps_idx_f[b * NPOINT + c_local];
  const float cx = xb[ci * 3 + 0];
  const float cy = xb[ci * 3 + 1];
  const float cz = xb[ci * 3 + 2];
  const float R2 = 0.01f;  // f32(0.1*0.1), numpy weak-scalar promotion
  const unsigned long long below = (1ull << lane) - 1ull;

  int cnt = 0;
#pragma unroll 4
  for (int r = 0; r < 64; ++r) {
    const int p0 = r * 128 + lane;
    const int p1 = p0 + 64;
    float ax = xb[p0 * 3 + 0], ay = xb[p0 * 3 + 1], az = xb[p0 * 3 + 2];
    float bx = xb[p1 * 3 + 0], by = xb[p1 * 3 + 1], bz = xb[p1 * 3 + 2];
    float dxa = __fsub_rn(ax, cx), dya = __fsub_rn(ay, cy), dza = __fsub_rn(az, cz);
    float dxb = __fsub_rn(bx, cx), dyb = __fsub_rn(by, cy), dzb = __fsub_rn(bz, cz);
    float d2a = __fadd_rn(__fadd_rn(__fmul_rn(dxa, dxa), __fmul_rn(dya, dya)), __fmul_rn(dza, dza));
    float d2b = __fadd_rn(__fadd_rn(__fmul_rn(dxb, dxb), __fmul_rn(dyb, dyb)), __fmul_rn(dzb, dzb));
    const bool i0 = d2a < R2;
    const bool i1 = d2b < R2;
    const unsigned long long m0 = __ballot(i0);
    if (i0) {
      int pos = cnt + (int)__popcll(m0 & below);
      if (pos < NSAMPLE) slots[w * NSAMPLE + pos] = p0;
    }
    cnt += (int)__popcll(m0);
    const unsigned long long m1 = __ballot(i1);
    if (i1) {
      int pos = cnt + (int)__popcll(m1 & below);
      if (pos < NSAMPLE) slots[w * NSAMPLE + pos] = p1;
    }
    cnt += (int)__popcll(m1);
  }
  if (lane < NSAMPLE) {
    const int first = (cnt > 0) ? slots[w * NSAMPLE] : 0;
    const int v = (lane < cnt) ? slots[w * NSAMPLE + lane] : first;
    sids_f[((size_t)(b * NPOINT + c_local)) * NSAMPLE + lane] = (float)v;
  }
}

// ------------------------------------------------------- gather + MLP + max
// 32 lanes = 32 samples, 2 centers per wave, 8 centers per 256-thr block.
// Weights are wave-uniform -> read directly from global (scalar-load path,
// L2-hot: 66 KB shared by all 512 blocks). No LDS, no block barrier.
// h1/h2 fully unrolled so they stay in registers; (256,2) = 256-VGPR budget.
__global__ __launch_bounds__(256, 2) void k_mlp(const float* __restrict__ xyz,
                                                const float* __restrict__ feat,
                                                const unsigned short* __restrict__ feat_t,
                                                const float* __restrict__ fps_idx_f,
                                                const float* __restrict__ sids_f,
                                                const float* __restrict__ w0g,
                                                const float* __restrict__ b0g,
                                                const float* __restrict__ w1g,
                                                const float* __restrict__ b1g,
                                                const float* __restrict__ w2g,
                                                const float* __restrict__ b2g,
                                                float* __restrict__ out_feat,
                                                int Ntot, int useT) {
  const int t = threadIdx.x;
  const int b = blockIdx.x >> 6;
  const int c_local = (blockIdx.x & 63) * 8 + (t >> 5);
  const int s = t & 31;
  const int ci = (int)fps_idx_f[b * NPOINT + c_local];
  const float cx = xyz[((size_t)b * NPB + ci) * 3 + 0];
  const float cy = xyz[((size_t)b * NPB + ci) * 3 + 1];
  const float cz = xyz[((size_t)b * NPB + ci) * 3 + 2];
  const int id = (int)sids_f[((size_t)(b * NPOINT + c_local)) * NSAMPLE + s];

  float g[67];
  {
    const size_t pb = ((size_t)b * NPB + id) * 3;
    g[0] = __fsub_rn(xyz[pb + 0], cx);
    g[1] = __fsub_rn(xyz[pb + 1], cy);
    g[2] = __fsub_rn(xyz[pb + 2], cz);
    if (useT) {
      const uint4* fp = reinterpret_cast<const uint4*>(feat_t + ((size_t)b * NPB + id) * 64);
#pragma unroll
      for (int v = 0; v < 8; ++v) {
        uint4 r = fp[v];
        unsigned int vs[4] = {r.x, r.y, r.z, r.w};
#pragma unroll
        for (int q = 0; q < 4; ++q) {
          g[3 + v * 8 + q * 2 + 0] = __uint_as_float(vs[q] << 16);
          g[3 + v * 8 + q * 2 + 1] = __uint_as_float(vs[q] & 0xFFFF0000u);
        }
      }
    } else {
      const float* col = feat + (size_t)(b * NPB + id);
#pragma unroll 8
      for (int c = 0; c < 64; ++c) g[3 + c] = col[(size_t)c * Ntot];
    }
  }

  float h1[64];
#pragma unroll
  for (int o = 0; o < 64; ++o) {
    float acc = b0g[o];
    const float* wr = w0g + o * 67;
#pragma unroll
    for (int c = 0; c < 67; ++c) acc += wr[c] * g[c];
    h1[o] = fmaxf(acc, 0.0f);
  }
  float h2[64];
#pragma unroll
  for (int o = 0; o < 64; ++o) {
    float acc = b1g[o];
    const float* wr = w1g + o * 64;
#pragma unroll
    for (int c = 0; c < 64; ++c) acc += wr[c] * h1[c];
    h2[o] = fmaxf(acc, 0.0f);
  }
#pragma unroll 1
  for (int o = 0; o < 128; ++o) {
    float acc = b2g[o];
    const float* wr = w2g + o * 64;
#pragma unroll
    for (int c = 0; c < 64; ++c) acc += wr[c] * h2[c];
    float v = fmaxf(acc, 0.0f);
#pragma unroll
    for (int off = 16; off >= 1; off >>= 1) v = fmaxf(v, __shfl_xor(v, off));
    if (s == 0) out_feat[((size_t)b * 128 + o) * NPOINT + c_local] = v;
  }
}

// ------------------------------------------------------------------- launch
extern "C" void kernel_launch(void* const* d_in, const int* in_sizes, int n_in,
                              void* d_out, int out_size, void* d_ws, size_t ws_size,
                              hipStream_t stream) {
  (void)n_in; (void)out_size;
  const float* xyz = (const float*)d_in[0];
  const float* feat = (const float*)d_in[1];
  // d_in[2] = num_points (8192, fixed by setup)
  const float* w0 = (const float*)d_in[3];
  const float* b0 = (const float*)d_in[4];
  const float* w1 = (const float*)d_in[5];
  const float* b1 = (const float*)d_in[6];
  const float* w2 = (const float*)d_in[7];
  const float* b2 = (const float*)d_in[8];

  const int Ntot = in_sizes[0] / 3;   // 65536
  const int B = Ntot / NPB;           // 8

  float* out = (float*)d_out;
  float* o_xyz = out;                                    // [B,512,3]
  float* o_idx = o_xyz + (size_t)B * NPOINT * 3;         // [B,512]
  float* o_feat = o_idx + (size_t)B * NPOINT;            // [B,128,512]
  float* o_sids = o_feat + (size_t)B * 128 * NPOINT;     // [B,512,32]

  // Workspace: only the transposed-features buffer (bf16), only if it fits.
  const size_t ft_bytes = (size_t)Ntot * 64 * 2;         // 8 MB
  const int useT = (ws_size >= ft_bytes) ? 1 : 0;
  unsigned short* ft_ws = (unsigned short*)d_ws;

  if (useT) {
    k_transpose<<<dim3(Ntot / 64), dim3(256), 0, stream>>>(feat, ft_ws, Ntot);
  }
  k_fps<<<dim3(B), dim3(512), 0, stream>>>(xyz, o_xyz, o_idx);
  k_ball<<<dim3(B * 64), dim3(512), 0, stream>>>(xyz, o_idx, o_sids);
  k_mlp<<<dim3(B * 64), dim3(256), 0, stream>>>(xyz, feat, ft_ws, o_idx, o_sids,
                                                w0, b0, w1, b1, w2, b2, o_feat,
                                                Ntot, useT);
}

// Round 7
// 951.142 us; speedup vs baseline: 1.0109x; 1.0109x over previous
//
#include <hip/hip_runtime.h>
#include <cstdint>
#include <cstddef>

#define NPOINT 512
#define NSAMPLE 32
#define NPB 8192  // points per batch

// Inputs: float32. Outputs: float32 flat concat (new_xyz, new_idx,
// new_features, sample_ids). Selection math (FPS argmax, ball d2<r2) must be
// bit-exact vs numpy f32: __f*_rn ops, no FMA contraction, exact tie-breaks.
__device__ __forceinline__ unsigned short f2bf(float f) {
  unsigned int u = __float_as_uint(f);
  unsigned int r = u + 0x7FFFu + ((u >> 16) & 1u);  // RNE
  return (unsigned short)(r >> 16);
}

// ---------------------------------------------------------------- FPS
// One block (512 thr) per batch; thread t owns points [t*16, t*16+16).
// r5/r6 pathology: with const __restrict inputs the compiler kept only ~60
// VGPRs and RE-LOADED the 48 coord values from global every iteration
// (L2-bound, ~3000 cyc/iter). Countermeasures: (a) 64 explicit scalar
// locals (no arrays), (b) out_xyz/out_idx are NOT __restrict, so the
// per-iteration stores may alias xyz and re-loading coords is illegal ->
// they must stay in registers, (c) (512,2) gives a 256-VGPR budget so no
// scratch spill is needed.
#define FPS_UPD(J)                                                             \
  do {                                                                         \
    float dx_ = __fsub_rn(px##J, qx);                                          \
    float dy_ = __fsub_rn(py##J, qy);                                          \
    float dz_ = __fsub_rn(pz##J, qz);                                          \
    float s_ = __fadd_rn(__fadd_rn(__fmul_rn(dx_, dx_), __fmul_rn(dy_, dy_)),  \
                         __fmul_rn(dz_, dz_));                                 \
    d##J = fminf(d##J, s_);                                                    \
  } while (0)

#define FPS_CHK(J)                                                             \
  if (d##J == wmax) { bi = J; wx = px##J; wy = py##J; wz = pz##J; }

__global__ __launch_bounds__(512, 2) void k_fps(const float* __restrict__ xyz,
                                                float* out_xyz,
                                                float* out_idx) {
  const int b = blockIdx.x;
  const int t = threadIdx.x;
  const float* xb = xyz + (size_t)b * NPB * 3;

  const float4* gp = reinterpret_cast<const float4*>(xb + (size_t)t * 48);
  float4 v0 = gp[0], v1 = gp[1], v2 = gp[2], v3 = gp[3];
  float4 v4 = gp[4], v5 = gp[5], v6 = gp[6], v7 = gp[7];
  float4 v8 = gp[8], v9 = gp[9], v10 = gp[10], v11 = gp[11];
  float px0 = v0.x,  py0 = v0.y,  pz0 = v0.z;
  float px1 = v0.w,  py1 = v1.x,  pz1 = v1.y;
  float px2 = v1.z,  py2 = v1.w,  pz2 = v2.x;
  float px3 = v2.y,  py3 = v2.z,  pz3 = v2.w;
  float px4 = v3.x,  py4 = v3.y,  pz4 = v3.z;
  float px5 = v3.w,  py5 = v4.x,  pz5 = v4.y;
  float px6 = v4.z,  py6 = v4.w,  pz6 = v5.x;
  float px7 = v5.y,  py7 = v5.z,  pz7 = v5.w;
  float px8 = v6.x,  py8 = v6.y,  pz8 = v6.z;
  float px9 = v6.w,  py9 = v7.x,  pz9 = v7.y;
  float px10 = v7.z, py10 = v7.w, pz10 = v8.x;
  float px11 = v8.y, py11 = v8.z, pz11 = v8.w;
  float px12 = v9.x, py12 = v9.y, pz12 = v9.z;
  float px13 = v9.w, py13 = v10.x, pz13 = v10.y;
  float px14 = v10.z, py14 = v10.w, pz14 = v11.x;
  float px15 = v11.y, py15 = v11.z, pz15 = v11.w;
  float d0 = 1e10f, d1 = 1e10f, d2 = 1e10f, d3 = 1e10f;
  float d4 = 1e10f, d5 = 1e10f, d6 = 1e10f, d7 = 1e10f;
  float d8 = 1e10f, d9 = 1e10f, d10 = 1e10f, d11 = 1e10f;
  float d12 = 1e10f, d13 = 1e10f, d14 = 1e10f, d15 = 1e10f;

  __shared__ __align__(16) float sD[2][8];
  __shared__ int sI[2][8];
  __shared__ float sX[2][8], sY[2][8], sZ[2][8];

  const int wid = t >> 6;
  const int lane = t & 63;

  float qx = xb[0], qy = xb[1], qz = xb[2];  // selection 0 = index 0
  if (t == 0) {
    out_idx[b * NPOINT + 0] = 0.0f;
    size_t o = (size_t)(b * NPOINT) * 3;
    out_xyz[o + 0] = qx; out_xyz[o + 1] = qy; out_xyz[o + 2] = qz;
  }

  for (int it = 1; it < NPOINT; ++it) {
    FPS_UPD(0);  FPS_UPD(1);  FPS_UPD(2);  FPS_UPD(3);
    FPS_UPD(4);  FPS_UPD(5);  FPS_UPD(6);  FPS_UPD(7);
    FPS_UPD(8);  FPS_UPD(9);  FPS_UPD(10); FPS_UPD(11);
    FPS_UPD(12); FPS_UPD(13); FPS_UPD(14); FPS_UPD(15);
    // per-thread max via fmax tree (v_max3-friendly)
    float m01 = fmaxf(d0, d1),   m23 = fmaxf(d2, d3);
    float m45 = fmaxf(d4, d5),   m67 = fmaxf(d6, d7);
    float m89 = fmaxf(d8, d9),   mab = fmaxf(d10, d11);
    float mcd = fmaxf(d12, d13), mef = fmaxf(d14, d15);
    float q0 = fmaxf(fmaxf(m01, m23), fmaxf(m45, m67));
    float q1 = fmaxf(fmaxf(m89, mab), fmaxf(mcd, mef));
    float best = fmaxf(q0, q1);
    // wave-level max
    float wmax = best;
#pragma unroll
    for (int off = 32; off >= 1; off >>= 1) wmax = fmaxf(wmax, __shfl_xor(wmax, off));
    const unsigned long long m = __ballot(best == wmax);
    const int p = it & 1;
    if (lane == (int)(__ffsll((unsigned long long)m) - 1)) {  // lowest tied lane
      // recover smallest local index equal to wmax (descending overrides)
      int bi = 15; float wx = px15, wy = py15, wz = pz15;
      FPS_CHK(14) FPS_CHK(13) FPS_CHK(12) FPS_CHK(11)
      FPS_CHK(10) FPS_CHK(9)  FPS_CHK(8)  FPS_CHK(7)
      FPS_CHK(6)  FPS_CHK(5)  FPS_CHK(4)  FPS_CHK(3)
      FPS_CHK(2)  FPS_CHK(1)  FPS_CHK(0)
      sD[p][wid] = wmax;
      sI[p][wid] = t * 16 + bi;
      sX[p][wid] = wx; sY[p][wid] = wy; sZ[p][wid] = wz;
    }
    __syncthreads();  // the only barrier per iteration
    float bd = sD[p][0];
    int bw = 0;
#pragma unroll
    for (int w = 1; w < 8; ++w) {
      float d_ = sD[p][w];
      if (d_ > bd) { bd = d_; bw = w; }
    }
    const int gbi = sI[p][bw];
    qx = sX[p][bw]; qy = sY[p][bw]; qz = sZ[p][bw];
    if (t == 0) {
      out_idx[b * NPOINT + it] = (float)gbi;
      size_t o = (size_t)(b * NPOINT + it) * 3;
      out_xyz[o + 0] = qx; out_xyz[o + 1] = qy; out_xyz[o + 2] = qz;
    }
  }
}

// ---------------------------------------------------------- feature transpose
// features f32 [64][Ntot] -> feat_t bf16 [Ntot][64]
__global__ __launch_bounds__(256) void k_transpose(const float* __restrict__ in,
                                                   unsigned short* __restrict__ out,
                                                   int Ntot) {
  __shared__ __align__(16) unsigned short tile[64][65];
  const int t = threadIdx.x;
  const int n0 = blockIdx.x * 64;
#pragma unroll
  for (int i = 0; i < 16; ++i) {
    int c = i * 4 + (t >> 6);
    int n = t & 63;
    tile[c][n] = f2bf(in[(size_t)c * Ntot + n0 + n]);
  }
  __syncthreads();
#pragma unroll
  for (int i = 0; i < 16; ++i) {
    int n = i * 4 + (t >> 6);
    int c = t & 63;
    out[(size_t)(n0 + n) * 64 + c] = tile[c][n];
  }
}

// ---------------------------------------------------------------- ball query
// One wave per center (8 waves/block). Fixed 64 rounds x 2 points/lane so
// loads pipeline across rounds. Ordered compaction via ballot+popcount.
__global__ __launch_bounds__(512) void k_ball(const float* __restrict__ xyz,
                                              const float* __restrict__ fps_idx_f,
                                              float* __restrict__ sids_f) {
  __shared__ int slots[8 * NSAMPLE];
  const int b = blockIdx.x >> 6;
  const int cbase = (blockIdx.x & 63) * 8;
  const int t = threadIdx.x;
  const float* xb = xyz + (size_t)b * NPB * 3;

  const int w = t >> 6, lane = t & 63;
  const int c_local = cbase + w;
  const int ci = (int)fps_idx_f[b * NPOINT + c_local];
  const float cx = xb[ci * 3 + 0];
  const float cy = xb[ci * 3 + 1];
  const float cz = xb[ci * 3 + 2];
  const float R2 = 0.01f;  // f32(0.1*0.1), numpy weak-scalar promotion
  const unsigned long long below = (1ull << lane) - 1ull;

  int cnt = 0;
#pragma unroll 4
  for (int r = 0; r < 64; ++r) {
    const int p0 = r * 128 + lane;
    const int p1 = p0 + 64;
    float ax = xb[p0 * 3 + 0], ay = xb[p0 * 3 + 1], az = xb[p0 * 3 + 2];
    float bx = xb[p1 * 3 + 0], by = xb[p1 * 3 + 1], bz = xb[p1 * 3 + 2];
    float dxa = __fsub_rn(ax, cx), dya = __fsub_rn(ay, cy), dza = __fsub_rn(az, cz);
    float dxb = __fsub_rn(bx, cx), dyb = __fsub_rn(by, cy), dzb = __fsub_rn(bz, cz);
    float d2a = __fadd_rn(__fadd_rn(__fmul_rn(dxa, dxa), __fmul_rn(dya, dya)), __fmul_rn(dza, dza));
    float d2b = __fadd_rn(__fadd_rn(__fmul_rn(dxb, dxb), __fmul_rn(dyb, dyb)), __fmul_rn(dzb, dzb));
    const bool i0 = d2a < R2;
    const bool i1 = d2b < R2;
    const unsigned long long m0 = __ballot(i0);
    if (i0) {
      int pos = cnt + (int)__popcll(m0 & below);
      if (pos < NSAMPLE) slots[w * NSAMPLE + pos] = p0;
    }
    cnt += (int)__popcll(m0);
    const unsigned long long m1 = __ballot(i1);
    if (i1) {
      int pos = cnt + (int)__popcll(m1 & below);
      if (pos < NSAMPLE) slots[w * NSAMPLE + pos] = p1;
    }
    cnt += (int)__popcll(m1);
  }
  if (lane < NSAMPLE) {
    const int first = (cnt > 0) ? slots[w * NSAMPLE] : 0;
    const int v = (lane < cnt) ? slots[w * NSAMPLE + lane] : first;
    sids_f[((size_t)(b * NPOINT + c_local)) * NSAMPLE + lane] = (float)v;
  }
}

// ------------------------------------------------------- gather + MLP + max
// 32 lanes = 32 samples, 2 centers per wave, 8 centers per 256-thr block.
// W0/W2 f32 in LDS, W1 bf16 in LDS (~59 KB). h1/h2 in registers.
// (r6 lesson: global/scalar weight reads regressed ~70 us; LDS staging wins.)
__global__ __launch_bounds__(256) void k_mlp(const float* __restrict__ xyz,
                                             const float* __restrict__ feat,
                                             const unsigned short* __restrict__ feat_t,
                                             const float* __restrict__ fps_idx_f,
                                             const float* __restrict__ sids_f,
                                             const float* __restrict__ w0g,
                                             const float* __restrict__ b0g,
                                             const float* __restrict__ w1g,
                                             const float* __restrict__ b1g,
                                             const float* __restrict__ w2g,
                                             const float* __restrict__ b2g,
                                             float* __restrict__ out_feat,
                                             int Ntot, int useT) {
  __shared__ __align__(16) float W0s[64 * 68];            // padded rows (c 67 = 0)
  __shared__ __align__(16) unsigned short W1s[64 * 64];   // bf16
  __shared__ __align__(16) float W2s[128 * 64];
  __shared__ float b0s[64], b1s[64], b2s[128];
  const int t = threadIdx.x;
  for (int i = t; i < 64 * 68; i += 256) {
    int r = i / 68, c = i - r * 68;
    W0s[i] = (c < 67) ? w0g[r * 67 + c] : 0.0f;
  }
  for (int i = t; i < 64 * 64; i += 256) W1s[i] = f2bf(w1g[i]);
  for (int i = t; i < 128 * 64; i += 256) W2s[i] = w2g[i];
  if (t < 64) b0s[t] = b0g[t];
  if (t < 64) b1s[t] = b1g[t];
  if (t < 128) b2s[t] = b2g[t];
  __syncthreads();

  const int b = blockIdx.x >> 6;
  const int c_local = (blockIdx.x & 63) * 8 + (t >> 5);
  const int s = t & 31;
  const int ci = (int)fps_idx_f[b * NPOINT + c_local];
  const float cx = xyz[((size_t)b * NPB + ci) * 3 + 0];
  const float cy = xyz[((size_t)b * NPB + ci) * 3 + 1];
  const float cz = xyz[((size_t)b * NPB + ci) * 3 + 2];
  const int id = (int)sids_f[((size_t)(b * NPOINT + c_local)) * NSAMPLE + s];

  float g[68];
  {
    const size_t pb = ((size_t)b * NPB + id) * 3;
    g[0] = __fsub_rn(xyz[pb + 0], cx);
    g[1] = __fsub_rn(xyz[pb + 1], cy);
    g[2] = __fsub_rn(xyz[pb + 2], cz);
    if (useT) {
      const uint4* fp = reinterpret_cast<const uint4*>(feat_t + ((size_t)b * NPB + id) * 64);
#pragma unroll
      for (int v = 0; v < 8; ++v) {
        uint4 r = fp[v];
        unsigned int vs[4] = {r.x, r.y, r.z, r.w};
#pragma unroll
        for (int q = 0; q < 4; ++q) {
          g[3 + v * 8 + q * 2 + 0] = __uint_as_float(vs[q] << 16);
          g[3 + v * 8 + q * 2 + 1] = __uint_as_float(vs[q] & 0xFFFF0000u);
        }
      }
    } else {
      const float* col = feat + (size_t)(b * NPB + id);
#pragma unroll 8
      for (int c = 0; c < 64; ++c) g[3 + c] = col[(size_t)c * Ntot];
    }
    g[67] = 0.0f;
  }

  float h1[64];
#pragma unroll
  for (int o = 0; o < 64; ++o) {
    float acc = b0s[o];
    const float4* wp = reinterpret_cast<const float4*>(&W0s[o * 68]);
#pragma unroll
    for (int c4 = 0; c4 < 17; ++c4) {
      float4 wv = wp[c4];
      acc += wv.x * g[c4 * 4 + 0];
      acc += wv.y * g[c4 * 4 + 1];
      acc += wv.z * g[c4 * 4 + 2];
      acc += wv.w * g[c4 * 4 + 3];
    }
    h1[o] = fmaxf(acc, 0.0f);
  }
  float h2[64];
#pragma unroll
  for (int o = 0; o < 64; ++o) {
    float acc = b1s[o];
    const uint2* wp = reinterpret_cast<const uint2*>(&W1s[o * 64]);
#pragma unroll
    for (int c4 = 0; c4 < 16; ++c4) {
      uint2 u = wp[c4];
      acc += __uint_as_float(u.x << 16) * h1[c4 * 4 + 0];
      acc += __uint_as_float(u.x & 0xFFFF0000u) * h1[c4 * 4 + 1];
      acc += __uint_as_float(u.y << 16) * h1[c4 * 4 + 2];
      acc += __uint_as_float(u.y & 0xFFFF0000u) * h1[c4 * 4 + 3];
    }
    h2[o] = fmaxf(acc, 0.0f);
  }
#pragma unroll 1
  for (int o = 0; o < 128; ++o) {
    float acc = b2s[o];
    const float4* wp = reinterpret_cast<const float4*>(&W2s[o * 64]);
#pragma unroll
    for (int c4 = 0; c4 < 16; ++c4) {
      float4 wv = wp[c4];
      acc += wv.x * h2[c4 * 4 + 0];
      acc += wv.y * h2[c4 * 4 + 1];
      acc += wv.z * h2[c4 * 4 + 2];
      acc += wv.w * h2[c4 * 4 + 3];
    }
    float v = fmaxf(acc, 0.0f);
#pragma unroll
    for (int off = 16; off >= 1; off >>= 1) v = fmaxf(v, __shfl_xor(v, off));
    if (s == 0) out_feat[((size_t)b * 128 + o) * NPOINT + c_local] = v;
  }
}

// ------------------------------------------------------------------- launch
extern "C" void kernel_launch(void* const* d_in, const int* in_sizes, int n_in,
                              void* d_out, int out_size, void* d_ws, size_t ws_size,
                              hipStream_t stream) {
  (void)n_in; (void)out_size;
  const float* xyz = (const float*)d_in[0];
  const float* feat = (const float*)d_in[1];
  // d_in[2] = num_points (8192, fixed by setup)
  const float* w0 = (const float*)d_in[3];
  const float* b0 = (const float*)d_in[4];
  const float* w1 = (const float*)d_in[5];
  const float* b1 = (const float*)d_in[6];
  const float* w2 = (const float*)d_in[7];
  const float* b2 = (const float*)d_in[8];

  const int Ntot = in_sizes[0] / 3;   // 65536
  const int B = Ntot / NPB;           // 8

  float* out = (float*)d_out;
  float* o_xyz = out;                                    // [B,512,3]
  float* o_idx = o_xyz + (size_t)B * NPOINT * 3;         // [B,512]
  float* o_feat = o_idx + (size_t)B * NPOINT;            // [B,128,512]
  float* o_sids = o_feat + (size_t)B * 128 * NPOINT;     // [B,512,32]

  // Workspace: only the transposed-features buffer (bf16), only if it fits.
  const size_t ft_bytes = (size_t)Ntot * 64 * 2;         // 8 MB
  const int useT = (ws_size >= ft_bytes) ? 1 : 0;
  unsigned short* ft_ws = (unsigned short*)d_ws;

  if (useT) {
    k_transpose<<<dim3(Ntot / 64), dim3(256), 0, stream>>>(feat, ft_ws, Ntot);
  }
  k_fps<<<dim3(B), dim3(512), 0, stream>>>(xyz, o_xyz, o_idx);
  k_ball<<<dim3(B * 64), dim3(512), 0, stream>>>(xyz, o_idx, o_sids);
  k_mlp<<<dim3(B * 64), dim3(256), 0, stream>>>(xyz, feat, ft_ws, o_idx, o_sids,
                                                w0, b0, w1, b1, w2, b2, o_feat,
                                                Ntot, useT);
}

// Round 8
// 919.619 us; speedup vs baseline: 1.0456x; 1.0343x over previous
//
#include <hip/hip_runtime.h>
#include <cstdint>
#include <cstddef>

#define NPOINT 512
#define NSAMPLE 32
#define NPB 8192  // points per batch

// Inputs: float32. Outputs: float32 flat concat (new_xyz, new_idx,
// new_features, sample_ids). Selection math (FPS argmax, ball d2<r2) must be
// bit-exact vs numpy f32: __f*_rn ops, no FMA contraction, exact tie-breaks.
__device__ __forceinline__ unsigned short f2bf(float f) {
  unsigned int u = __float_as_uint(f);
  unsigned int r = u + 0x7FFFu + ((u >> 16) & 1u);  // RNE
  return (unsigned short)(r >> 16);
}

// ---------------------------------------------------------------- FPS
// One block (512 thr) per batch; thread t owns points [t*16, t*16+16).
// r5-r7 pathology: coords defined by loads from a const __restrict pointer
// get REMATERIALIZED (re-loaded from L2 every iteration, ~60 VGPR, ~3000
// cyc/iter) no matter the launch-bounds budget. Fix: pipe the 48 coords
// through a no-op inline asm with "+v" constraints -> their defs become
// asm results, re-loading is impossible, they must live in VGPRs (~80 live
// vs 256 budget from (512,2), so no spill either).
#define FPS_UPD(J)                                                             \
  do {                                                                         \
    float dx_ = __fsub_rn(px##J, qx);                                          \
    float dy_ = __fsub_rn(py##J, qy);                                          \
    float dz_ = __fsub_rn(pz##J, qz);                                          \
    float s_ = __fadd_rn(__fadd_rn(__fmul_rn(dx_, dx_), __fmul_rn(dy_, dy_)),  \
                         __fmul_rn(dz_, dz_));                                 \
    d##J = fminf(d##J, s_);                                                    \
  } while (0)

#define FPS_CHK(J)                                                             \
  if (d##J == wmax) { bi = J; wx = px##J; wy = py##J; wz = pz##J; }

__global__ __launch_bounds__(512, 2) void k_fps(const float* __restrict__ xyz,
                                                float* __restrict__ out_xyz,
                                                float* __restrict__ out_idx) {
  const int b = blockIdx.x;
  const int t = threadIdx.x;
  const float* xb = xyz + (size_t)b * NPB * 3;

  const float4* gp = reinterpret_cast<const float4*>(xb + (size_t)t * 48);
  float4 v0 = gp[0], v1 = gp[1], v2 = gp[2], v3 = gp[3];
  float4 v4 = gp[4], v5 = gp[5], v6 = gp[6], v7 = gp[7];
  float4 v8 = gp[8], v9 = gp[9], v10 = gp[10], v11 = gp[11];
  float px0 = v0.x,  py0 = v0.y,  pz0 = v0.z;
  float px1 = v0.w,  py1 = v1.x,  pz1 = v1.y;
  float px2 = v1.z,  py2 = v1.w,  pz2 = v2.x;
  float px3 = v2.y,  py3 = v2.z,  pz3 = v2.w;
  float px4 = v3.x,  py4 = v3.y,  pz4 = v3.z;
  float px5 = v3.w,  py5 = v4.x,  pz5 = v4.y;
  float px6 = v4.z,  py6 = v4.w,  pz6 = v5.x;
  float px7 = v5.y,  py7 = v5.z,  pz7 = v5.w;
  float px8 = v6.x,  py8 = v6.y,  pz8 = v6.z;
  float px9 = v6.w,  py9 = v7.x,  pz9 = v7.y;
  float px10 = v7.z, py10 = v7.w, pz10 = v8.x;
  float px11 = v8.y, py11 = v8.z, pz11 = v8.w;
  float px12 = v9.x, py12 = v9.y, pz12 = v9.z;
  float px13 = v9.w, py13 = v10.x, pz13 = v10.y;
  float px14 = v10.z, py14 = v10.w, pz14 = v11.x;
  float px15 = v11.y, py15 = v11.z, pz15 = v11.w;

  // Opaque-ify: defs become asm outputs -> rematerialization impossible.
  asm volatile("" : "+v"(px0), "+v"(py0), "+v"(pz0), "+v"(px1), "+v"(py1),
                    "+v"(pz1), "+v"(px2), "+v"(py2));
  asm volatile("" : "+v"(pz2), "+v"(px3), "+v"(py3), "+v"(pz3), "+v"(px4),
                    "+v"(py4), "+v"(pz4), "+v"(px5));
  asm volatile("" : "+v"(py5), "+v"(pz5), "+v"(px6), "+v"(py6), "+v"(pz6),
                    "+v"(px7), "+v"(py7), "+v"(pz7));
  asm volatile("" : "+v"(px8), "+v"(py8), "+v"(pz8), "+v"(px9), "+v"(py9),
                    "+v"(pz9), "+v"(px10), "+v"(py10));
  asm volatile("" : "+v"(pz10), "+v"(px11), "+v"(py11), "+v"(pz11),
                    "+v"(px12), "+v"(py12), "+v"(pz12), "+v"(px13));
  asm volatile("" : "+v"(py13), "+v"(pz13), "+v"(px14), "+v"(py14),
                    "+v"(pz14), "+v"(px15), "+v"(py15), "+v"(pz15));

  float d0 = 1e10f, d1 = 1e10f, d2 = 1e10f, d3 = 1e10f;
  float d4 = 1e10f, d5 = 1e10f, d6 = 1e10f, d7 = 1e10f;
  float d8 = 1e10f, d9 = 1e10f, d10 = 1e10f, d11 = 1e10f;
  float d12 = 1e10f, d13 = 1e10f, d14 = 1e10f, d15 = 1e10f;

  __shared__ __align__(16) float sD[2][8];
  __shared__ int sI[2][8];
  __shared__ float sX[2][8], sY[2][8], sZ[2][8];

  const int wid = t >> 6;
  const int lane = t & 63;

  float qx = xb[0], qy = xb[1], qz = xb[2];  // selection 0 = index 0
  if (t == 0) {
    out_idx[b * NPOINT + 0] = 0.0f;
    size_t o = (size_t)(b * NPOINT) * 3;
    out_xyz[o + 0] = qx; out_xyz[o + 1] = qy; out_xyz[o + 2] = qz;
  }

  for (int it = 1; it < NPOINT; ++it) {
    FPS_UPD(0);  FPS_UPD(1);  FPS_UPD(2);  FPS_UPD(3);
    FPS_UPD(4);  FPS_UPD(5);  FPS_UPD(6);  FPS_UPD(7);
    FPS_UPD(8);  FPS_UPD(9);  FPS_UPD(10); FPS_UPD(11);
    FPS_UPD(12); FPS_UPD(13); FPS_UPD(14); FPS_UPD(15);
    // per-thread max via fmax tree (v_max3-friendly)
    float m01 = fmaxf(d0, d1),   m23 = fmaxf(d2, d3);
    float m45 = fmaxf(d4, d5),   m67 = fmaxf(d6, d7);
    float m89 = fmaxf(d8, d9),   mab = fmaxf(d10, d11);
    float mcd = fmaxf(d12, d13), mef = fmaxf(d14, d15);
    float q0 = fmaxf(fmaxf(m01, m23), fmaxf(m45, m67));
    float q1 = fmaxf(fmaxf(m89, mab), fmaxf(mcd, mef));
    float best = fmaxf(q0, q1);
    // wave-level max
    float wmax = best;
#pragma unroll
    for (int off = 32; off >= 1; off >>= 1) wmax = fmaxf(wmax, __shfl_xor(wmax, off));
    const unsigned long long m = __ballot(best == wmax);
    const int p = it & 1;
    if (lane == (int)(__ffsll((unsigned long long)m) - 1)) {  // lowest tied lane
      // recover smallest local index equal to wmax (descending overrides)
      int bi = 15; float wx = px15, wy = py15, wz = pz15;
      FPS_CHK(14) FPS_CHK(13) FPS_CHK(12) FPS_CHK(11)
      FPS_CHK(10) FPS_CHK(9)  FPS_CHK(8)  FPS_CHK(7)
      FPS_CHK(6)  FPS_CHK(5)  FPS_CHK(4)  FPS_CHK(3)
      FPS_CHK(2)  FPS_CHK(1)  FPS_CHK(0)
      sD[p][wid] = wmax;
      sI[p][wid] = t * 16 + bi;
      sX[p][wid] = wx; sY[p][wid] = wy; sZ[p][wid] = wz;
    }
    __syncthreads();  // the only barrier per iteration
    float bd = sD[p][0];
    int bw = 0;
#pragma unroll
    for (int w = 1; w < 8; ++w) {
      float d_ = sD[p][w];
      if (d_ > bd) { bd = d_; bw = w; }
    }
    const int gbi = sI[p][bw];
    qx = sX[p][bw]; qy = sY[p][bw]; qz = sZ[p][bw];
    if (t == 0) {
      out_idx[b * NPOINT + it] = (float)gbi;
      size_t o = (size_t)(b * NPOINT + it) * 3;
      out_xyz[o + 0] = qx; out_xyz[o + 1] = qy; out_xyz[o + 2] = qz;
    }
  }
}

// ---------------------------------------------------------- feature transpose
// features f32 [64][Ntot] -> feat_t bf16 [Ntot][64]
__global__ __launch_bounds__(256) void k_transpose(const float* __restrict__ in,
                                                   unsigned short* __restrict__ out,
                                                   int Ntot) {
  __shared__ __align__(16) unsigned short tile[64][65];
  const int t = threadIdx.x;
  const int n0 = blockIdx.x * 64;
#pragma unroll
  for (int i = 0; i < 16; ++i) {
    int c = i * 4 + (t >> 6);
    int n = t & 63;
    tile[c][n] = f2bf(in[(size_t)c * Ntot + n0 + n]);
  }
  __syncthreads();
#pragma unroll
  for (int i = 0; i < 16; ++i) {
    int n = i * 4 + (t >> 6);
    int c = t & 63;
    out[(size_t)(n0 + n) * 64 + c] = tile[c][n];
  }
}

// ---------------------------------------------------------------- ball query
// One wave per center (8 waves/block). Fixed 64 rounds x 2 points/lane so
// loads pipeline across rounds. Ordered compaction via ballot+popcount.
__global__ __launch_bounds__(512) void k_ball(const float* __restrict__ xyz,
                                              const float* __restrict__ fps_idx_f,
                                              float* __restrict__ sids_f) {
  __shared__ int slots[8 * NSAMPLE];
  const int b = blockIdx.x >> 6;
  const int cbase = (blockIdx.x & 63) * 8;
  const int t = threadIdx.x;
  const float* xb = xyz + (size_t)b * NPB * 3;

  const int w = t >> 6, lane = t & 63;
  const int c_local = cbase + w;
  const int ci = (int)fps_idx_f[b * NPOINT + c_local];
  const float cx = xb[ci * 3 + 0];
  const float cy = xb[ci * 3 + 1];
  const float cz = xb[ci * 3 + 2];
  const float R2 = 0.01f;  // f32(0.1*0.1), numpy weak-scalar promotion
  const unsigned long long below = (1ull << lane) - 1ull;

  int cnt = 0;
#pragma unroll 4
  for (int r = 0; r < 64; ++r) {
    const int p0 = r * 128 + lane;
    const int p1 = p0 + 64;
    float ax = xb[p0 * 3 + 0], ay = xb[p0 * 3 + 1], az = xb[p0 * 3 + 2];
    float bx = xb[p1 * 3 + 0], by = xb[p1 * 3 + 1], bz = xb[p1 * 3 + 2];
    float dxa = __fsub_rn(ax, cx), dya = __fsub_rn(ay, cy), dza = __fsub_rn(az, cz);
    float dxb = __fsub_rn(bx, cx), dyb = __fsub_rn(by, cy), dzb = __fsub_rn(bz, cz);
    float d2a = __fadd_rn(__fadd_rn(__fmul_rn(dxa, dxa), __fmul_rn(dya, dya)), __fmul_rn(dza, dza));
    float d2b = __fadd_rn(__fadd_rn(__fmul_rn(dxb, dxb), __fmul_rn(dyb, dyb)), __fmul_rn(dzb, dzb));
    const bool i0 = d2a < R2;
    const bool i1 = d2b < R2;
    const unsigned long long m0 = __ballot(i0);
    if (i0) {
      int pos = cnt + (int)__popcll(m0 & below);
      if (pos < NSAMPLE) slots[w * NSAMPLE + pos] = p0;
    }
    cnt += (int)__popcll(m0);
    const unsigned long long m1 = __ballot(i1);
    if (i1) {
      int pos = cnt + (int)__popcll(m1 & below);
      if (pos < NSAMPLE) slots[w * NSAMPLE + pos] = p1;
    }
    cnt += (int)__popcll(m1);
  }
  if (lane < NSAMPLE) {
    const int first = (cnt > 0) ? slots[w * NSAMPLE] : 0;
    const int v = (lane < cnt) ? slots[w * NSAMPLE + lane] : first;
    sids_f[((size_t)(b * NPOINT + c_local)) * NSAMPLE + lane] = (float)v;
  }
}

// ------------------------------------------------------- gather + MLP + max
// 32 lanes = 32 samples, 2 centers per wave, 8 centers per 256-thr block.
// W0/W2 f32 in LDS, W1 bf16 in LDS (~59 KB). h1/h2 in registers.
// (r6 lesson: global/scalar weight reads regressed ~70 us; LDS staging wins.)
__global__ __launch_bounds__(256) void k_mlp(const float* __restrict__ xyz,
                                             const float* __restrict__ feat,
                                             const unsigned short* __restrict__ feat_t,
                                             const float* __restrict__ fps_idx_f,
                                             const float* __restrict__ sids_f,
                                             const float* __restrict__ w0g,
                                             const float* __restrict__ b0g,
                                             const float* __restrict__ w1g,
                                             const float* __restrict__ b1g,
                                             const float* __restrict__ w2g,
                                             const float* __restrict__ b2g,
                                             float* __restrict__ out_feat,
                                             int Ntot, int useT) {
  __shared__ __align__(16) float W0s[64 * 68];            // padded rows (c 67 = 0)
  __shared__ __align__(16) unsigned short W1s[64 * 64];   // bf16
  __shared__ __align__(16) float W2s[128 * 64];
  __shared__ float b0s[64], b1s[64], b2s[128];
  const int t = threadIdx.x;
  for (int i = t; i < 64 * 68; i += 256) {
    int r = i / 68, c = i - r * 68;
    W0s[i] = (c < 67) ? w0g[r * 67 + c] : 0.0f;
  }
  for (int i = t; i < 64 * 64; i += 256) W1s[i] = f2bf(w1g[i]);
  for (int i = t; i < 128 * 64; i += 256) W2s[i] = w2g[i];
  if (t < 64) b0s[t] = b0g[t];
  if (t < 64) b1s[t] = b1g[t];
  if (t < 128) b2s[t] = b2g[t];
  __syncthreads();

  const int b = blockIdx.x >> 6;
  const int c_local = (blockIdx.x & 63) * 8 + (t >> 5);
  const int s = t & 31;
  const int ci = (int)fps_idx_f[b * NPOINT + c_local];
  const float cx = xyz[((size_t)b * NPB + ci) * 3 + 0];
  const float cy = xyz[((size_t)b * NPB + ci) * 3 + 1];
  const float cz = xyz[((size_t)b * NPB + ci) * 3 + 2];
  const int id = (int)sids_f[((size_t)(b * NPOINT + c_local)) * NSAMPLE + s];

  float g[68];
  {
    const size_t pb = ((size_t)b * NPB + id) * 3;
    g[0] = __fsub_rn(xyz[pb + 0], cx);
    g[1] = __fsub_rn(xyz[pb + 1], cy);
    g[2] = __fsub_rn(xyz[pb + 2], cz);
    if (useT) {
      const uint4* fp = reinterpret_cast<const uint4*>(feat_t + ((size_t)b * NPB + id) * 64);
#pragma unroll
      for (int v = 0; v < 8; ++v) {
        uint4 r = fp[v];
        unsigned int vs[4] = {r.x, r.y, r.z, r.w};
#pragma unroll
        for (int q = 0; q < 4; ++q) {
          g[3 + v * 8 + q * 2 + 0] = __uint_as_float(vs[q] << 16);
          g[3 + v * 8 + q * 2 + 1] = __uint_as_float(vs[q] & 0xFFFF0000u);
        }
      }
    } else {
      const float* col = feat + (size_t)(b * NPB + id);
#pragma unroll 8
      for (int c = 0; c < 64; ++c) g[3 + c] = col[(size_t)c * Ntot];
    }
    g[67] = 0.0f;
  }

  float h1[64];
#pragma unroll
  for (int o = 0; o < 64; ++o) {
    float acc = b0s[o];
    const float4* wp = reinterpret_cast<const float4*>(&W0s[o * 68]);
#pragma unroll
    for (int c4 = 0; c4 < 17; ++c4) {
      float4 wv = wp[c4];
      acc += wv.x * g[c4 * 4 + 0];
      acc += wv.y * g[c4 * 4 + 1];
      acc += wv.z * g[c4 * 4 + 2];
      acc += wv.w * g[c4 * 4 + 3];
    }
    h1[o] = fmaxf(acc, 0.0f);
  }
  float h2[64];
#pragma unroll
  for (int o = 0; o < 64; ++o) {
    float acc = b1s[o];
    const uint2* wp = reinterpret_cast<const uint2*>(&W1s[o * 64]);
#pragma unroll
    for (int c4 = 0; c4 < 16; ++c4) {
      uint2 u = wp[c4];
      acc += __uint_as_float(u.x << 16) * h1[c4 * 4 + 0];
      acc += __uint_as_float(u.x & 0xFFFF0000u) * h1[c4 * 4 + 1];
      acc += __uint_as_float(u.y << 16) * h1[c4 * 4 + 2];
      acc += __uint_as_float(u.y & 0xFFFF0000u) * h1[c4 * 4 + 3];
    }
    h2[o] = fmaxf(acc, 0.0f);
  }
#pragma unroll 1
  for (int o = 0; o < 128; ++o) {
    float acc = b2s[o];
    const float4* wp = reinterpret_cast<const float4*>(&W2s[o * 64]);
#pragma unroll
    for (int c4 = 0; c4 < 16; ++c4) {
      float4 wv = wp[c4];
      acc += wv.x * h2[c4 * 4 + 0];
      acc += wv.y * h2[c4 * 4 + 1];
      acc += wv.z * h2[c4 * 4 + 2];
      acc += wv.w * h2[c4 * 4 + 3];
    }
    float v = fmaxf(acc, 0.0f);
#pragma unroll
    for (int off = 16; off >= 1; off >>= 1) v = fmaxf(v, __shfl_xor(v, off));
    if (s == 0) out_feat[((size_t)b * 128 + o) * NPOINT + c_local] = v;
  }
}

// ------------------------------------------------------------------- launch
extern "C" void kernel_launch(void* const* d_in, const int* in_sizes, int n_in,
                              void* d_out, int out_size, void* d_ws, size_t ws_size,
                              hipStream_t stream) {
  (void)n_in; (void)out_size;
  const float* xyz = (const float*)d_in[0];
  const float* feat = (const float*)d_in[1];
  // d_in[2] = num_points (8192, fixed by setup)
  const float* w0 = (const float*)d_in[3];
  const float* b0 = (const float*)d_in[4];
  const float* w1 = (const float*)d_in[5];
  const float* b1 = (const float*)d_in[6];
  const float* w2 = (const float*)d_in[7];
  const float* b2 = (const float*)d_in[8];

  const int Ntot = in_sizes[0] / 3;   // 65536
  const int B = Ntot / NPB;           // 8

  float* out = (float*)d_out;
  float* o_xyz = out;                                    // [B,512,3]
  float* o_idx = o_xyz + (size_t)B * NPOINT * 3;         // [B,512]
  float* o_feat = o_idx + (size_t)B * NPOINT;            // [B,128,512]
  float* o_sids = o_feat + (size_t)B * 128 * NPOINT;     // [B,512,32]

  // Workspace: only the transposed-features buffer (bf16), only if it fits.
  const size_t ft_bytes = (size_t)Ntot * 64 * 2;         // 8 MB
  const int useT = (ws_size >= ft_bytes) ? 1 : 0;
  unsigned short* ft_ws = (unsigned short*)d_ws;

  if (useT) {
    k_transpose<<<dim3(Ntot / 64), dim3(256), 0, stream>>>(feat, ft_ws, Ntot);
  }
  k_fps<<<dim3(B), dim3(512), 0, stream>>>(xyz, o_xyz, o_idx);
  k_ball<<<dim3(B * 64), dim3(512), 0, stream>>>(xyz, o_idx, o_sids);
  k_mlp<<<dim3(B * 64), dim3(256), 0, stream>>>(xyz, feat, ft_ws, o_idx, o_sids,
                                                w0, b0, w1, b1, w2, b2, o_feat,
                                                Ntot, useT);
}